// Round 1
// baseline (204.896 us; speedup 1.0000x reference)
//
#include <hip/hip_runtime.h>

#define CCH 64
#define HW 128
#define TW 32
#define TH 8
#define HALO_W 34
#define HALO_H 10
#define NH (HALO_W * HALO_H)   // 340

__device__ __forceinline__ float lrelu(float x) { return x > 0.f ? x : 0.1f * x; }

// ---------------- prep: att-scaled depthwise kernels -> ws ----------------
__global__ __launch_bounds__(64) void dgfem_prep(
    const float* __restrict__ v, const float* __restrict__ ca_w1,
    const float* __restrict__ ca_w2, const float* __restrict__ k_w1,
    const float* __restrict__ k_w2, float* __restrict__ kernArr)
{
    const int b = blockIdx.x;
    const int t = threadIdx.x;           // 64 threads
    __shared__ float vb[64], t1[8], att[64], t2[64];

    vb[t] = v[b * 64 + t];
    __syncthreads();

    if (t < 8) {
        float s = 0.f;
        for (int j = 0; j < 64; ++j) s += vb[j] * ca_w1[t * 64 + j];
        t1[t] = lrelu(s);
    }
    {
        float s = 0.f;
        for (int j = 0; j < 64; ++j) s += vb[j] * k_w1[t * 64 + j];
        t2[t] = lrelu(s);
    }
    __syncthreads();
    {
        float s = 0.f;
        for (int i = 0; i < 8; ++i) s += t1[i] * ca_w2[t * 8 + i];
        att[t] = 1.f / (1.f + expf(-s));
    }
    __syncthreads();
    // 576 rows of k_w2; fold in att[c] (conv is linear: conv(x*a,k)=conv(x,a*k))
    for (int r = t; r < 576; r += 64) {
        float s = 0.f;
        for (int j = 0; j < 64; ++j) s += t2[j] * k_w2[r * 64 + j];
        kernArr[b * 576 + r] = s * att[r / 9];
    }
}

// ---------------- fused: depthwise 3x3 + lrelu + 1x1 conv + bias ----------------
__global__ __launch_bounds__(256) void dgfem_main(
    const float* __restrict__ x0, const float* __restrict__ kernArr,
    const float* __restrict__ conv_w, const float* __restrict__ conv_b,
    float* __restrict__ out)
{
    const int t  = threadIdx.x;          // 256
    const int b  = blockIdx.z;
    const int tx = blockIdx.x * TW;
    const int ty = blockIdx.y * TH;
    const int px = t & (TW - 1);
    const int py = t >> 5;

    __shared__ float wT[64 * 64];        // wT[c*64+o] = conv_w[o*64+c]
    __shared__ float bias[64];
    __shared__ float xs[2][NH];
    __shared__ float ks[2][12];

    for (int i = t; i < 4096; i += 256) {
        int o = i >> 6, c = i & 63;
        wT[c * 64 + o] = conv_w[i];      // coalesced read, transposed scatter
    }
    if (t < 64) bias[t] = conv_b[t];

    float acc[64];
    #pragma unroll
    for (int o = 0; o < 64; ++o) acc[o] = 0.f;

    const size_t bbase = (size_t)b * CCH * HW * HW;

    // stage channel 0 into buffer 0
    {
        const float* xc = x0 + bbase;
        for (int i = t; i < NH; i += 256) {
            int lx = i % HALO_W, ly = i / HALO_W;
            int gx = tx + lx - 1, gy = ty + ly - 1;
            xs[0][i] = ((unsigned)gx < HW && (unsigned)gy < HW) ? xc[gy * HW + gx] : 0.f;
        }
        if (t < 9) ks[0][t] = kernArr[(b * 64) * 9 + t];
    }
    __syncthreads();

    for (int c = 0; c < 64; ++c) {
        const int cur = c & 1;
        if (c < 63) {   // prefetch next channel into the other buffer
            const float* xc = x0 + bbase + (size_t)(c + 1) * HW * HW;
            for (int i = t; i < NH; i += 256) {
                int lx = i % HALO_W, ly = i / HALO_W;
                int gx = tx + lx - 1, gy = ty + ly - 1;
                xs[cur ^ 1][i] = ((unsigned)gx < HW && (unsigned)gy < HW) ? xc[gy * HW + gx] : 0.f;
            }
            if (t < 9) ks[cur ^ 1][t] = kernArr[(b * 64 + c + 1) * 9 + t];
        }

        // depthwise 3x3 (cross-correlation, pad 1) + lrelu
        float yv = 0.f;
        #pragma unroll
        for (int dy = 0; dy < 3; ++dy)
            #pragma unroll
            for (int dx = 0; dx < 3; ++dx)
                yv += ks[cur][dy * 3 + dx] * xs[cur][(py + dy) * HALO_W + (px + dx)];
        yv = lrelu(yv);

        // 1x1 conv accumulate: acc[o] += w[o][c] * yv  (broadcast float4 LDS reads)
        const float4* w4 = (const float4*)&wT[c * 64];
        #pragma unroll
        for (int o4 = 0; o4 < 16; ++o4) {
            float4 wv = w4[o4];
            acc[o4 * 4 + 0] += wv.x * yv;
            acc[o4 * 4 + 1] += wv.y * yv;
            acc[o4 * 4 + 2] += wv.z * yv;
            acc[o4 * 4 + 3] += wv.w * yv;
        }
        __syncthreads();   // staging done + compute reads done before reuse
    }

    float* op = out + bbase + (size_t)(ty + py) * HW + (tx + px);
    #pragma unroll
    for (int o = 0; o < 64; ++o)
        op[(size_t)o * HW * HW] = acc[o] + bias[o];
}

extern "C" void kernel_launch(void* const* d_in, const int* in_sizes, int n_in,
                              void* d_out, int out_size, void* d_ws, size_t ws_size,
                              hipStream_t stream) {
    const float* x0     = (const float*)d_in[0];
    const float* v      = (const float*)d_in[1];
    const float* ca_w1  = (const float*)d_in[2];
    const float* ca_w2  = (const float*)d_in[3];
    const float* k_w1   = (const float*)d_in[4];
    const float* k_w2   = (const float*)d_in[5];
    const float* conv_w = (const float*)d_in[6];
    const float* conv_b = (const float*)d_in[7];
    float* kernArr = (float*)d_ws;       // 32*64*9 floats = 73728 B
    float* outp    = (float*)d_out;

    dgfem_prep<<<dim3(32), dim3(64), 0, stream>>>(v, ca_w1, ca_w2, k_w1, k_w2, kernArr);
    dgfem_main<<<dim3(HW / TW, HW / TH, 32), dim3(256), 0, stream>>>(
        x0, kernArr, conv_w, conv_b, outp);
}